// Round 3
// baseline (281.842 us; speedup 1.0000x reference)
//
#include <hip/hip_runtime.h>

// B=2, T=2048, C=1024, H=16, HD=64, ALPHA=32
// softmax((att - globalmax)*ALPHA) == softmax(att*ALPHA): the global-max shift
// cancels (softmax shift-invariant; -inf mask applied after the shift).
// Net: causal SDPA with scale 1/sqrt(HD)=0.125, all matmuls in bf16 MFMA.
// Q is pre-scaled by 0.125*log2(e) in the QKV-projection epilogue; attention
// softmax runs UN-SHIFTED in the exp2 domain, no online max, no cross-lane
// reductions (row-sum l via MFMA w/ ones).
//
// Round 1: QKV projection on 256x256/BK=64 8-phase counted-vmcnt schedule.
// Round 2: attn triple-buffered K/V with counted vmcnt; sum-balanced pairing
//          (measured: solo-wave tail dominated -> only 63.4 -> 60.7).
// Round 3: attn: (a) cost-FLAT block mapping xr=(x&7)*2+(x>>3): co-resident
// candidates at id-distance 8/16/256 get equal or ±1-rank tile counts, so
// every CU keeps 2 waves/SIMD for its whole makespan (R2 pairing left heavy
// blocks solo for ~94% of time: 2*2600 + 30*4400 ~= 145K cyc measured);
// (b) cross-tile S/PV pipeline: PV(t-1) runs from registers (vf/pf slot
// t&1, manual 2x unroll keeps indices static) and interleaves under tile
// t's exp2/pack chain -- legal because unshifted softmax needs no rescale.
// lgkmcnt(0) before each end-of-iter barrier retires cross-iter V reads
// before other waves stage into that buffer.

#define Bsz 2
#define Tsz 2048
#define Csz 1024
#define Hsz 16
#define HDsz 64

typedef __bf16 bf16;
typedef __bf16 bf16x8 __attribute__((ext_vector_type(8)));
typedef __bf16 bf16x4 __attribute__((ext_vector_type(4)));
typedef float float4v __attribute__((ext_vector_type(4)));

#define MFMA16(a, b, c) __builtin_amdgcn_mfma_f32_16x16x32_bf16(a, b, c, 0, 0, 0)

// async global->LDS, 16B per lane; LDS dest must be lane-linear within a wave
#define GLOAD_LDS16(gptr, lptr)                                      \
  __builtin_amdgcn_global_load_lds(                                  \
      (const __attribute__((address_space(1))) void*)(gptr),         \
      (__attribute__((address_space(3))) void*)(lptr), 16, 0, 0)

// ---------------------------------------------------------------------------
// cast f32 -> bf16, 3 tensors batched via grid.z, 8 elems/thread
// ---------------------------------------------------------------------------
__global__ __launch_bounds__(256) void cast3_bf16(
    const float* __restrict__ q, const float* __restrict__ k,
    const float* __restrict__ v, bf16* __restrict__ oq,
    bf16* __restrict__ ok, bf16* __restrict__ ov) {
  const int z = blockIdx.z;
  const float* src = z == 0 ? q : (z == 1 ? k : v);
  bf16* dst = z == 0 ? oq : (z == 1 ? ok : ov);
  const size_t i = ((size_t)blockIdx.x * 256 + threadIdx.x) * 8;
  const float4 a = *(const float4*)(src + i);
  const float4 b = *(const float4*)(src + i + 4);
  bf16x8 o;
  o[0] = (bf16)a.x; o[1] = (bf16)a.y; o[2] = (bf16)a.z; o[3] = (bf16)a.w;
  o[4] = (bf16)b.x; o[5] = (bf16)b.y; o[6] = (bf16)b.z; o[7] = (bf16)b.w;
  *(bf16x8*)(dst + i) = o;
}

// ---------------------------------------------------------------------------
// weight transpose+cast: W[K,N] f32 -> WT[N,K] bf16; grid.z selects Wq/Wk/Wv/Wp
// ---------------------------------------------------------------------------
__global__ __launch_bounds__(256) void wtrans_bf16(
    const float* __restrict__ Wq, const float* __restrict__ Wk,
    const float* __restrict__ Wv, const float* __restrict__ Wp,
    bf16* __restrict__ WT) {
  const int z = blockIdx.z;
  const float* W = z == 0 ? Wq : (z == 1 ? Wk : (z == 2 ? Wv : Wp));
  bf16* out = WT + (size_t)z * (Csz * Csz);
  __shared__ float Ts[64][68];
  const int k0 = blockIdx.y * 64, n0 = blockIdx.x * 64;
  const int tid = threadIdx.x;
#pragma unroll
  for (int it = 0; it < 4; ++it) {
    const int idx = it * 256 + tid;
    const int r = idx >> 4, c4 = (idx & 15) * 4;
    *(float4*)&Ts[r][c4] = *(const float4*)(W + (size_t)(k0 + r) * Csz + n0 + c4);
  }
  __syncthreads();
#pragma unroll
  for (int it = 0; it < 2; ++it) {
    const int idx = it * 256 + tid;
    const int n = idx & 63, k8 = (idx >> 6) * 8;
    bf16x8 o;
#pragma unroll
    for (int j = 0; j < 8; ++j) o[j] = (bf16)Ts[k8 + j][n];
    *(bf16x8*)(out + (size_t)(n0 + n) * Csz + k0 + k8) = o;
  }
}

// ---------------------------------------------------------------------------
// QKV projection: 256x256 tile, BK=64, 512 thr = 8 waves (2Mx4N), 8-phase
// counted-vmcnt schedule (unchanged; verified round 1).
// ---------------------------------------------------------------------------
__global__ __launch_bounds__(512, 2) void gemm256_qkv(
    const bf16* __restrict__ A0, const bf16* __restrict__ A1,
    const bf16* __restrict__ A2, const bf16* __restrict__ Wt,
    const float* __restrict__ b0, const float* __restrict__ b1,
    const float* __restrict__ b2, bf16* __restrict__ C0,
    bf16* __restrict__ C1, bf16* __restrict__ Vt) {
  constexpr int NT = Csz / 64;  // 16 K-tiles
  const int z = blockIdx.z;
  const bf16* A = z == 0 ? A0 : (z == 1 ? A1 : A2);
  const float* bias = z == 0 ? b0 : (z == 1 ? b1 : b2);
  const bf16* Bt = Wt + (size_t)z * (Csz * Csz);
  const int m0 = blockIdx.y * 256;
  const int nz0 = blockIdx.x * 256;

  __shared__ bf16 As[2 * 256 * 64];
  __shared__ bf16 Bs[2 * 256 * 64];

  const int tid = threadIdx.x;
  const int wave = tid >> 6, lane = tid & 63;
  const int l15 = lane & 15, quad = lane >> 4;
  const int wm = wave >> 2, wn = wave & 3;

  const int srow = tid >> 3;  // 0..63
  const int sch = tid & 7;
  const bf16* Ab = A + (size_t)(m0 + srow) * Csz + (sch ^ (srow & 7)) * 8;
  const bf16* Bb = Bt + (size_t)(nz0 + srow) * Csz + (sch ^ (srow & 7)) * 8;

#define STG(Xb, lds, lbuf, hh, tt)                                           \
  {                                                                          \
    GLOAD_LDS16((Xb) + (size_t)((hh)*128) * Csz + (size_t)(tt)*64,           \
                &(lds)[(lbuf) * (256 * 64) + (hh)*8192 + tid * 8]);          \
    GLOAD_LDS16((Xb) + (size_t)((hh)*128 + 64) * Csz + (size_t)(tt)*64,     \
                &(lds)[(lbuf) * (256 * 64) + (hh)*8192 + 4096 + tid * 8]);  \
  }
#define RD_A(dst, lbuf, i2, ks)                                              \
  dst = *(const bf16x8*)&As[(lbuf) * (256 * 64) +                            \
                            (wm * 128 + (i2)*16 + l15) * 64 +                \
                            ((((ks)*4 + quad) ^ (l15 & 7)) * 8)];
#define RD_B(dst, lbuf, j2, ks)                                              \
  dst = *(const bf16x8*)&Bs[(lbuf) * (256 * 64) +                            \
                            (wn * 64 + (j2)*16 + l15) * 64 +                 \
                            ((((ks)*4 + quad) ^ (l15 & 7)) * 8)];

  float4v acc[8][4];
#pragma unroll
  for (int i = 0; i < 8; ++i)
#pragma unroll
    for (int j = 0; j < 4; ++j) acc[i][j] = (float4v){0.f, 0.f, 0.f, 0.f};

  // prologue: tile0 all 4 halves, tile1 A-halves (12 loads/thread total)
  STG(Ab, As, 0, 0, 0);
  STG(Ab, As, 0, 1, 0);
  STG(Bb, Bs, 0, 0, 0);
  STG(Bb, Bs, 0, 1, 0);
  STG(Ab, As, 1, 0, 1);
  STG(Ab, As, 1, 1, 1);
  asm volatile("s_waitcnt vmcnt(4)" ::: "memory");
  __builtin_amdgcn_s_barrier();
  __builtin_amdgcn_sched_barrier(0);

#pragma unroll 1
  for (int t = 0; t < NT; ++t) {
    const int bsel = t & 1;
    bf16x8 af0[4][2], af1[4][2], bf0[2][2], bf1[2][2];

    // ---- P1: quadrant (0,0) --------------------------------------------
#pragma unroll
    for (int i = 0; i < 4; ++i) {
      RD_A(af0[i][0], bsel, i, 0);
      RD_A(af0[i][1], bsel, i, 1);
    }
#pragma unroll
    for (int j = 0; j < 2; ++j) {
      RD_B(bf0[j][0], bsel, j, 0);
      RD_B(bf0[j][1], bsel, j, 1);
    }
    if (t + 1 < NT) STG(Bb, Bs, bsel ^ 1, 0, t + 1);
    __builtin_amdgcn_s_barrier();
    asm volatile("s_waitcnt lgkmcnt(0)" ::: "memory");
    __builtin_amdgcn_sched_barrier(0);
    __builtin_amdgcn_s_setprio(1);
#pragma unroll
    for (int i = 0; i < 4; ++i)
#pragma unroll
      for (int j = 0; j < 2; ++j) {
        acc[i][j] = MFMA16(af0[i][0], bf0[j][0], acc[i][j]);
        acc[i][j] = MFMA16(af0[i][1], bf0[j][1], acc[i][j]);
      }
    __builtin_amdgcn_s_setprio(0);
    __builtin_amdgcn_s_barrier();

    // ---- P2: quadrant (1,0) --------------------------------------------
#pragma unroll
    for (int i = 0; i < 4; ++i) {
      RD_A(af1[i][0], bsel, 4 + i, 0);
      RD_A(af1[i][1], bsel, 4 + i, 1);
    }
    if (t + 1 < NT) STG(Bb, Bs, bsel ^ 1, 1, t + 1);
    __builtin_amdgcn_s_barrier();
    asm volatile("s_waitcnt lgkmcnt(0)" ::: "memory");
    __builtin_amdgcn_sched_barrier(0);
    __builtin_amdgcn_s_setprio(1);
#pragma unroll
    for (int i = 0; i < 4; ++i)
#pragma unroll
      for (int j = 0; j < 2; ++j) {
        acc[4 + i][j] = MFMA16(af1[i][0], bf0[j][0], acc[4 + i][j]);
        acc[4 + i][j] = MFMA16(af1[i][1], bf0[j][1], acc[4 + i][j]);
      }
    __builtin_amdgcn_s_setprio(0);
    __builtin_amdgcn_s_barrier();

    // ---- P3: quadrant (0,1) --------------------------------------------
#pragma unroll
    for (int j = 0; j < 2; ++j) {
      RD_B(bf1[j][0], bsel, 2 + j, 0);
      RD_B(bf1[j][1], bsel, 2 + j, 1);
    }
    if (t + 2 < NT) STG(Ab, As, bsel, 0, t + 2);
    __builtin_amdgcn_s_barrier();
    asm volatile("s_waitcnt lgkmcnt(0)" ::: "memory");
    __builtin_amdgcn_sched_barrier(0);
    __builtin_amdgcn_s_setprio(1);
#pragma unroll
    for (int i = 0; i < 4; ++i)
#pragma unroll
      for (int j = 0; j < 2; ++j) {
        acc[i][2 + j] = MFMA16(af0[i][0], bf1[j][0], acc[i][2 + j]);
        acc[i][2 + j] = MFMA16(af0[i][1], bf1[j][1], acc[i][2 + j]);
      }
    __builtin_amdgcn_s_setprio(0);
    __builtin_amdgcn_s_barrier();

    // ---- P4: quadrant (1,1) --------------------------------------------
    if (t + 2 < NT) STG(Ab, As, bsel, 1, t + 2);
    __builtin_amdgcn_s_barrier();
    __builtin_amdgcn_s_setprio(1);
#pragma unroll
    for (int i = 0; i < 4; ++i)
#pragma unroll
      for (int j = 0; j < 2; ++j) {
        acc[4 + i][2 + j] = MFMA16(af1[i][0], bf1[j][0], acc[4 + i][2 + j]);
        acc[4 + i][2 + j] = MFMA16(af1[i][1], bf1[j][1], acc[4 + i][2 + j]);
      }
    __builtin_amdgcn_s_setprio(0);
    if (t + 2 < NT) {
      asm volatile("s_waitcnt vmcnt(4)" ::: "memory");
    } else if (t + 1 < NT) {
      asm volatile("s_waitcnt vmcnt(0)" ::: "memory");
    }
    __builtin_amdgcn_s_barrier();
    __builtin_amdgcn_sched_barrier(0);
  }
#undef STG
#undef RD_A
#undef RD_B

  const int omb0 = m0 + wm * 128 + quad * 4;
  const int onb0 = nz0 + wn * 64 + l15;
  if (z == 2) {
#pragma unroll
    for (int j = 0; j < 4; ++j) {
      const int n = onb0 + j * 16;
      const float bj = bias[n];
#pragma unroll
      for (int i = 0; i < 8; ++i) {
        const int mrow = omb0 + i * 16;
        const int bb = mrow >> 11, tt = mrow & (Tsz - 1);
        union { bf16 h[4]; uint2 u; } pk;
#pragma unroll
        for (int r = 0; r < 4; ++r) pk.h[r] = (bf16)(acc[i][j][r] + bj);
        *(uint2*)(Vt + ((size_t)(bb * 1024 + n)) * Tsz + tt) = pk.u;
      }
    }
  } else {
    bf16* C = z == 0 ? C0 : C1;
    const float osc = z == 0 ? 0.180336880111124f : 1.0f;  // 0.125*log2(e)
#pragma unroll
    for (int j = 0; j < 4; ++j) {
      const float bj = bias[onb0 + j * 16];
#pragma unroll
      for (int i = 0; i < 8; ++i) {
#pragma unroll
        for (int r = 0; r < 4; ++r) {
          const float v = (acc[i][j][r] + bj) * osc;
          C[(size_t)(omb0 + i * 16 + r) * Csz + onb0 + j * 16] = (bf16)v;
        }
      }
    }
  }
}

// ---------------------------------------------------------------------------
// bf16 MFMA GEMM (m97 structure): kept for the output projection.
// ---------------------------------------------------------------------------
template <typename OutT, bool VTR>
__global__ __launch_bounds__(256) void gemm_mfma(
    const bf16* __restrict__ A0, const bf16* __restrict__ A1,
    const bf16* __restrict__ A2, const bf16* __restrict__ Wt,
    const float* __restrict__ b0, const float* __restrict__ b1,
    const float* __restrict__ b2, OutT* __restrict__ C0,
    OutT* __restrict__ C1, OutT* __restrict__ C2, int M, int N, int K) {
  const int z = blockIdx.z;
  const bf16* A = z == 0 ? A0 : (z == 1 ? A1 : A2);
  const float* bias = z == 0 ? b0 : (z == 1 ? b1 : b2);
  OutT* C = z == 0 ? C0 : (z == 1 ? C1 : C2);
  const bf16* Bt = Wt + (size_t)z * N * K;
  const float osc = (VTR && z == 0) ? 0.180336880111124f : 1.0f;

  __shared__ bf16 As[128 * 32];
  __shared__ bf16 Bs[128 * 32];
  const int tid = threadIdx.x;
  const int wave = tid >> 6, lane = tid & 63;
  const int l15 = lane & 15, quad = lane >> 4;
  const int m0 = blockIdx.y * 128, n0 = blockIdx.x * 128;
  const int wm = (wave >> 1) * 64, wn = (wave & 1) * 64;
  const int srow = tid >> 2, schunk = tid & 3;

  float4v acc[4][4];
#pragma unroll
  for (int i = 0; i < 4; ++i)
#pragma unroll
    for (int j = 0; j < 4; ++j) acc[i][j] = (float4v){0.f, 0.f, 0.f, 0.f};

  for (int k0 = 0; k0 < K; k0 += 32) {
    __syncthreads();
#pragma unroll
    for (int p = 0; p < 2; ++p) {
      const int row = p * 64 + srow;
      GLOAD_LDS16(A + (size_t)(m0 + row) * K + k0 + schunk * 8,
                  &As[(p * 256 + tid) * 8]);
      GLOAD_LDS16(Bt + (size_t)(n0 + row) * K + k0 + schunk * 8,
                  &Bs[(p * 256 + tid) * 8]);
    }
    __syncthreads();

    bf16x8 af[4], bfr[4];
#pragma unroll
    for (int i = 0; i < 4; ++i)
      af[i] = *(const bf16x8*)&As[(wm + i * 16 + l15) * 32 + quad * 8];
#pragma unroll
    for (int j = 0; j < 4; ++j)
      bfr[j] = *(const bf16x8*)&Bs[(wn + j * 16 + l15) * 32 + quad * 8];
#pragma unroll
    for (int i = 0; i < 4; ++i)
#pragma unroll
      for (int j = 0; j < 4; ++j)
        acc[i][j] = MFMA16(af[i], bfr[j], acc[i][j]);
  }

  const int omb = m0 + wm + quad * 4;
  const int onb = n0 + wn + l15;
  if (VTR && z == 2) {
#pragma unroll
    for (int j = 0; j < 4; ++j) {
      const int n = onb + j * 16;
      const float bj = bias[n];
#pragma unroll
      for (int i = 0; i < 4; ++i) {
        const int mrow = omb + i * 16;
        const int bb = mrow >> 11, t = mrow & (Tsz - 1);
        union { bf16 h[4]; uint2 u; } pk;
#pragma unroll
        for (int r = 0; r < 4; ++r) pk.h[r] = (bf16)(acc[i][j][r] + bj);
        *(uint2*)((bf16*)C + ((size_t)(bb * 1024 + n)) * Tsz + t) = pk.u;
      }
    }
  } else {
#pragma unroll
    for (int j = 0; j < 4; ++j) {
      const float bj = bias[onb + j * 16];
#pragma unroll
      for (int i = 0; i < 4; ++i) {
#pragma unroll
        for (int r = 0; r < 4; ++r) {
          const float v = (acc[i][j][r] + bj) * osc;
          const size_t off = (size_t)(omb + i * 16 + r) * N + onb + j * 16;
          if constexpr (sizeof(OutT) == 2)
            C[off] = (OutT)v;
          else
            C[off] = v;
        }
      }
    }
  }
}

// ---------------------------------------------------------------------------
// Flash attention, bf16 MFMA, S^T formulation.
// Round 3: cost-flat mapping + cross-tile S/PV register pipeline (see top).
// ---------------------------------------------------------------------------
__global__ __launch_bounds__(256) void attn_mfma(const bf16* __restrict__ Q,
                                                 const bf16* __restrict__ K,
                                                 const bf16* __restrict__ Vt,
                                                 bf16* __restrict__ Y) {
  __shared__ bf16 Ks[3][64 * 64];
  __shared__ bf16 Vs[3][64 * 64];
  __shared__ bf16 Ps[4][32 * 72];  // per-wave P[q][key], row stride 72

  const int bh = blockIdx.y;
  const int b = bh >> 4, h = bh & 15;
  // cost-flat mapping: blocks at id-distance 16 or 256 -> identical tile
  // count; distance 8 -> +-1 rank; distance 1 -> +-2 ranks.
  const int xr = (((int)blockIdx.x & 7) << 1) | ((int)blockIdx.x >> 3);
  const int i0 = xr * 128;
  const int tid = threadIdx.x;
  const int wave = tid >> 6, lane = tid & 63;
  const int l15 = lane & 15, quad = lane >> 4;

  const int srow = tid >> 3;  // 0..31
  const int sch = tid & 7;

  const bf16* kb = K + (size_t)b * Tsz * Csz + h * HDsz;
  const bf16* vb = Vt + (size_t)bh * HDsz * Tsz;

  const int qb = i0 + wave * 32;         // wave's first q row
  const int lastT = (qb + 31) >> 6;      // last active KV tile for this wave
  const int ntile = i0 / 64 + 2;         // keys 0 .. i0+127 (even, >= 2)

  bf16x8 qf[2][2];
#pragma unroll
  for (int sub = 0; sub < 2; ++sub) {
    const bf16* qp =
        Q + ((size_t)(b * Tsz + qb + sub * 16 + l15)) * Csz + h * HDsz + quad * 8;
    qf[sub][0] = *(const bf16x8*)qp;
    qf[sub][1] = *(const bf16x8*)(qp + 32);
  }

  bf16x8 ones;
#pragma unroll
  for (int j = 0; j < 8; ++j) ones[j] = (bf16)1.0f;

  float4v Of[2][4];
  float4v accl[2];
#pragma unroll
  for (int sub = 0; sub < 2; ++sub) {
    accl[sub] = (float4v){0.f, 0.f, 0.f, 0.f};
#pragma unroll
    for (int nc = 0; nc < 4; ++nc) Of[sub][nc] = (float4v){0.f, 0.f, 0.f, 0.f};
  }

  // stage K/V tile tt into LDS buffer bb: 4 loads/thread (2 K + 2 V)
#define STAGE_KV(tt, bb)                                                     \
  {                                                                          \
    _Pragma("unroll") for (int p = 0; p < 2; ++p) {                          \
      const int r = p * 32 + srow;                                           \
      const int c = sch ^ (r & 7);                                           \
      GLOAD_LDS16(kb + (size_t)((tt)*64 + r) * Csz + c * 8,                  \
                  &Ks[bb][(p * 256 + tid) * 8]);                             \
      GLOAD_LDS16(vb + (size_t)r * Tsz + (tt)*64 + c * 8,                    \
                  &Vs[bb][(p * 256 + tid) * 8]);                             \
    }                                                                        \
  }

  // cross-tile register state: slot = t & 1 (indices always literal)
  bf16x8 vf[2][4][2];  // [slot][nc][kc]  V^T A-frags of tile t
  bf16x8 pf[2][2][2];  // [slot][sub][kc] P^T B-frags of tile t

  // prologue: tiles 0,1 in flight; retire tile 0; barrier
  STAGE_KV(0, 0);
  STAGE_KV(1, 1);
  asm volatile("s_waitcnt vmcnt(4)" ::: "memory");
  __builtin_amdgcn_s_barrier();
  __builtin_amdgcn_sched_barrier(0);

  // Per iteration t (slot SL_ = t&1):
  //   stage(t+2) -> (t+2)%3 ; if active: vf[SL_] <- V(t), S(t) MFMA, mask,
  //   exp2 -> Ps ; PV(t-1) from pf/vf[SL_^1] (pure registers, overlaps) ;
  //   if active: pf[SL_] <- Ps ; vmcnt gate ; lgkmcnt(0) ; barrier.
#define ATTN_BODY(T_, SL_)                                                   \
  {                                                                          \
    const int t_ = (T_);                                                     \
    const int j0_ = t_ * 64;                                                 \
    const int bst_ = bcur == 0 ? 2 : bcur - 1;                               \
    if (t_ + 2 < ntile) STAGE_KV(t_ + 2, bst_);                              \
    const bool act_ = (t_ <= lastT);                                         \
    if (act_) {                                                              \
      _Pragma("unroll") for (int nc = 0; nc < 4; ++nc) {                     \
        const int row = nc * 16 + l15;                                       \
        _Pragma("unroll") for (int kc = 0; kc < 2; ++kc)                     \
            vf[SL_][nc][kc] = *(const bf16x8*)&Vs[bcur]                      \
                [row * 64 + (((kc * 4 + quad) ^ (row & 7)) * 8)];            \
      }                                                                      \
      float4v S[2][4];                                                       \
      _Pragma("unroll") for (int nc = 0; nc < 4; ++nc) {                     \
        const int row = nc * 16 + l15;                                       \
        const bf16x8 k0 = *(const bf16x8*)&Ks[bcur]                          \
            [row * 64 + ((quad ^ (row & 7)) * 8)];                           \
        const bf16x8 k1 = *(const bf16x8*)&Ks[bcur]                          \
            [row * 64 + (((quad + 4) ^ (row & 7)) * 8)];                     \
        _Pragma("unroll") for (int sub = 0; sub < 2; ++sub) {                \
          float4v a = (float4v){0.f, 0.f, 0.f, 0.f};                         \
          a = MFMA16(k0, qf[sub][0], a);                                     \
          a = MFMA16(k1, qf[sub][1], a);                                     \
          S[sub][nc] = a;                                                    \
        }                                                                    \
      }                                                                      \
      if (j0_ + 63 > qb) {                                                   \
        _Pragma("unroll") for (int sub = 0; sub < 2; ++sub) {                \
          const int q = qb + sub * 16 + l15;                                 \
          _Pragma("unroll") for (int nc = 0; nc < 4; ++nc) {                 \
            const int keyb = j0_ + nc * 16 + quad * 4;                       \
            _Pragma("unroll") for (int r = 0; r < 4; ++r)                    \
                if (keyb + r > q) S[sub][nc][r] = -1e30f;                    \
          }                                                                  \
        }                                                                    \
      }                                                                      \
      _Pragma("unroll") for (int sub = 0; sub < 2; ++sub) {                  \
        _Pragma("unroll") for (int nc = 0; nc < 4; ++nc) {                   \
          bf16x4 pk;                                                         \
          _Pragma("unroll") for (int r = 0; r < 4; ++r)                      \
              pk[r] = (bf16)__builtin_amdgcn_exp2f(S[sub][nc][r]);           \
          *(bf16x4*)&Ps[wave][(sub * 16 + l15) * 72 + nc * 16 + quad * 4] =  \
              pk;                                                            \
        }                                                                    \
      }                                                                      \
    }                                                                        \
    if (t_ >= 1 && t_ - 1 <= lastT) {                                        \
      _Pragma("unroll") for (int sub = 0; sub < 2; ++sub) {                  \
        accl[sub] = MFMA16(ones, pf[SL_ ^ 1][sub][0], accl[sub]);            \
        accl[sub] = MFMA16(ones, pf[SL_ ^ 1][sub][1], accl[sub]);            \
      }                                                                      \
      _Pragma("unroll") for (int nc = 0; nc < 4; ++nc)                       \
          _Pragma("unroll") for (int kc = 0; kc < 2; ++kc)                   \
              _Pragma("unroll") for (int sub = 0; sub < 2; ++sub)            \
                  Of[sub][nc] = MFMA16(vf[SL_ ^ 1][nc][kc],                  \
                                       pf[SL_ ^ 1][sub][kc], Of[sub][nc]);   \
    }                                                                        \
    if (act_) {                                                              \
      _Pragma("unroll") for (int sub = 0; sub < 2; ++sub)                    \
          _Pragma("unroll") for (int kc = 0; kc < 2; ++kc)                   \
              pf[SL_][sub][kc] = *(const bf16x8*)                            \
                  &Ps[wave][(sub * 16 + l15) * 72 + kc * 32 + quad * 8];     \
    }                                                                        \
    if (t_ + 2 < ntile) {                                                    \
      asm volatile("s_waitcnt vmcnt(4)" ::: "memory");                       \
    } else if (t_ + 1 < ntile) {                                             \
      asm volatile("s_waitcnt vmcnt(0)" ::: "memory");                       \
    }                                                                        \
    asm volatile("s_waitcnt lgkmcnt(0)" ::: "memory");                       \
    __builtin_amdgcn_sched_barrier(0);                                       \
    __builtin_amdgcn_s_barrier();                                            \
    __builtin_amdgcn_sched_barrier(0);                                       \
    bcur = bcur == 2 ? 0 : bcur + 1;                                         \
  }

  int bcur = 0;
#pragma unroll 1
  for (int tt = 0; tt < ntile; tt += 2) {
    ATTN_BODY(tt, 0);
    ATTN_BODY(tt + 1, 1);
  }
#undef ATTN_BODY
#undef STAGE_KV

  // drain: waves whose last active tile is ntile-1 (odd -> slot 1)
  if (lastT == ntile - 1) {
#pragma unroll
    for (int sub = 0; sub < 2; ++sub) {
      accl[sub] = MFMA16(ones, pf[1][sub][0], accl[sub]);
      accl[sub] = MFMA16(ones, pf[1][sub][1], accl[sub]);
    }
#pragma unroll
    for (int nc = 0; nc < 4; ++nc)
#pragma unroll
      for (int kc = 0; kc < 2; ++kc)
#pragma unroll
        for (int sub = 0; sub < 2; ++sub)
          Of[sub][nc] = MFMA16(vf[1][nc][kc], pf[1][sub][kc], Of[sub][nc]);
  }

  // ---- epilogue: Y[q][h*64+d] = O^T[d][q] / l[q]  (8B stores, r contiguous)
#pragma unroll
  for (int sub = 0; sub < 2; ++sub) {
    const float rl = __builtin_amdgcn_rcpf(accl[sub][0]);
    const size_t rowoff =
        ((size_t)(b * Tsz + qb + sub * 16 + l15)) * Csz + h * HDsz;
#pragma unroll
    for (int nc = 0; nc < 4; ++nc) {
      union { bf16 h4[4]; uint2 u; } pk;
#pragma unroll
      for (int r = 0; r < 4; ++r) pk.h4[r] = (bf16)(Of[sub][nc][r] * rl);
      *(uint2*)(Y + rowoff + nc * 16 + quad * 4) = pk.u;
    }
  }
}

extern "C" void kernel_launch(void* const* d_in, const int* in_sizes, int n_in,
                              void* d_out, int out_size, void* d_ws,
                              size_t ws_size, hipStream_t stream) {
  const float* query = (const float*)d_in[0];
  const float* key = (const float*)d_in[1];
  const float* value = (const float*)d_in[2];
  // d_in[3] = att_mask (tril causal) -- hard-coded in attn kernel
  const float* Wq = (const float*)d_in[4];
  const float* bq = (const float*)d_in[5];
  const float* Wk = (const float*)d_in[6];
  const float* bk = (const float*)d_in[7];
  const float* Wv = (const float*)d_in[8];
  const float* bv = (const float*)d_in[9];
  const float* Wp = (const float*)d_in[10];
  const float* bp = (const float*)d_in[11];
  float* out = (float*)d_out;

  char* ws = (char*)d_ws;
  bf16* WT = (bf16*)(ws);
  bf16* vc = (bf16*)(ws + (8u << 20));
  bf16* Qp = (bf16*)(ws + (16u << 20));
  bf16* Kp = (bf16*)(ws + (24u << 20));
  bf16* Vt = (bf16*)(ws + (32u << 20));
  bf16* Yb = vc;
  bf16* qc = (bf16*)d_out;
  bf16* kc = (bf16*)((char*)d_out + (8u << 20));

  const int M = Bsz * Tsz;  // 4096

  cast3_bf16<<<dim3((M * Csz) / (256 * 8), 1, 3), dim3(256), 0, stream>>>(
      query, key, value, qc, kc, vc);
  wtrans_bf16<<<dim3(16, 16, 4), dim3(256), 0, stream>>>(Wq, Wk, Wv, Wp, WT);
  // batched QKV projection, 256^2 8-phase; z==0 pre-scales Q; z==2 -> Vt
  gemm256_qkv<<<dim3(Csz / 256, M / 256, 3), dim3(512), 0, stream>>>(
      qc, kc, vc, WT, bq, bk, bv, Qp, Kp, Vt);
  // flash attention (writes bf16 into Yb = old vc slot)
  attn_mfma<<<dim3(Tsz / 128, Bsz * Hsz), dim3(256), 0, stream>>>(Qp, Kp, Vt,
                                                                  Yb);
  // output projection (f32 into d_out)
  gemm_mfma<float, false><<<dim3(Csz / 128, M / 128, 1), dim3(256), 0, stream>>>(
      Yb, Yb, Yb, WT + 3u * (Csz * Csz), bp, bp, bp, out, out, out, M, Csz,
      Csz);
}

// Round 4
// 246.487 us; speedup vs baseline: 1.1434x; 1.1434x over previous
//
#include <hip/hip_runtime.h>

// B=2, T=2048, C=1024, H=16, HD=64, ALPHA=32
// softmax((att - globalmax)*ALPHA) == softmax(att*ALPHA): the global-max shift
// cancels (softmax shift-invariant; -inf mask applied after the shift).
// Net: causal SDPA with scale 1/sqrt(HD)=0.125, all matmuls in bf16 MFMA.
// Q is pre-scaled by 0.125*log2(e) in the QKV-projection epilogue; attention
// softmax runs UN-SHIFTED in the exp2 domain, no online max, no cross-lane
// reductions (row-sum l via MFMA w/ ones).
//
// Round 1: QKV projection on 256x256/BK=64 8-phase counted-vmcnt schedule.
// Round 2: attn sum-balanced complementary mapping + triple-buffer (60.7us).
// Round 3: REGRESSED (equal-pair lockstep + longer chain + VGPR 132) - reverted.
// Round 4: R2 body/mapping, K/V DOUBLE-buffer -> LDS 51200 -> 3 blocks/CU
// (latency-bound loop: chain ~4270cyc/iter vs ~600cyc issue; more waves/SIMD
// is the lever; stage(t+1) issued a full iteration before its vmcnt(0) gate).

#define Bsz 2
#define Tsz 2048
#define Csz 1024
#define Hsz 16
#define HDsz 64

typedef __bf16 bf16;
typedef __bf16 bf16x8 __attribute__((ext_vector_type(8)));
typedef __bf16 bf16x4 __attribute__((ext_vector_type(4)));
typedef float float4v __attribute__((ext_vector_type(4)));

#define MFMA16(a, b, c) __builtin_amdgcn_mfma_f32_16x16x32_bf16(a, b, c, 0, 0, 0)

// async global->LDS, 16B per lane; LDS dest must be lane-linear within a wave
#define GLOAD_LDS16(gptr, lptr)                                      \
  __builtin_amdgcn_global_load_lds(                                  \
      (const __attribute__((address_space(1))) void*)(gptr),         \
      (__attribute__((address_space(3))) void*)(lptr), 16, 0, 0)

// ---------------------------------------------------------------------------
// cast f32 -> bf16, 3 tensors batched via grid.z, 8 elems/thread
// ---------------------------------------------------------------------------
__global__ __launch_bounds__(256) void cast3_bf16(
    const float* __restrict__ q, const float* __restrict__ k,
    const float* __restrict__ v, bf16* __restrict__ oq,
    bf16* __restrict__ ok, bf16* __restrict__ ov) {
  const int z = blockIdx.z;
  const float* src = z == 0 ? q : (z == 1 ? k : v);
  bf16* dst = z == 0 ? oq : (z == 1 ? ok : ov);
  const size_t i = ((size_t)blockIdx.x * 256 + threadIdx.x) * 8;
  const float4 a = *(const float4*)(src + i);
  const float4 b = *(const float4*)(src + i + 4);
  bf16x8 o;
  o[0] = (bf16)a.x; o[1] = (bf16)a.y; o[2] = (bf16)a.z; o[3] = (bf16)a.w;
  o[4] = (bf16)b.x; o[5] = (bf16)b.y; o[6] = (bf16)b.z; o[7] = (bf16)b.w;
  *(bf16x8*)(dst + i) = o;
}

// ---------------------------------------------------------------------------
// weight transpose+cast: W[K,N] f32 -> WT[N,K] bf16; grid.z selects Wq/Wk/Wv/Wp
// ---------------------------------------------------------------------------
__global__ __launch_bounds__(256) void wtrans_bf16(
    const float* __restrict__ Wq, const float* __restrict__ Wk,
    const float* __restrict__ Wv, const float* __restrict__ Wp,
    bf16* __restrict__ WT) {
  const int z = blockIdx.z;
  const float* W = z == 0 ? Wq : (z == 1 ? Wk : (z == 2 ? Wv : Wp));
  bf16* out = WT + (size_t)z * (Csz * Csz);
  __shared__ float Ts[64][68];
  const int k0 = blockIdx.y * 64, n0 = blockIdx.x * 64;
  const int tid = threadIdx.x;
#pragma unroll
  for (int it = 0; it < 4; ++it) {
    const int idx = it * 256 + tid;
    const int r = idx >> 4, c4 = (idx & 15) * 4;
    *(float4*)&Ts[r][c4] = *(const float4*)(W + (size_t)(k0 + r) * Csz + n0 + c4);
  }
  __syncthreads();
#pragma unroll
  for (int it = 0; it < 2; ++it) {
    const int idx = it * 256 + tid;
    const int n = idx & 63, k8 = (idx >> 6) * 8;
    bf16x8 o;
#pragma unroll
    for (int j = 0; j < 8; ++j) o[j] = (bf16)Ts[k8 + j][n];
    *(bf16x8*)(out + (size_t)(n0 + n) * Csz + k0 + k8) = o;
  }
}

// ---------------------------------------------------------------------------
// QKV projection: 256x256 tile, BK=64, 512 thr = 8 waves (2Mx4N), 8-phase
// counted-vmcnt schedule (unchanged; verified round 1).
// ---------------------------------------------------------------------------
__global__ __launch_bounds__(512, 2) void gemm256_qkv(
    const bf16* __restrict__ A0, const bf16* __restrict__ A1,
    const bf16* __restrict__ A2, const bf16* __restrict__ Wt,
    const float* __restrict__ b0, const float* __restrict__ b1,
    const float* __restrict__ b2, bf16* __restrict__ C0,
    bf16* __restrict__ C1, bf16* __restrict__ Vt) {
  constexpr int NT = Csz / 64;  // 16 K-tiles
  const int z = blockIdx.z;
  const bf16* A = z == 0 ? A0 : (z == 1 ? A1 : A2);
  const float* bias = z == 0 ? b0 : (z == 1 ? b1 : b2);
  const bf16* Bt = Wt + (size_t)z * (Csz * Csz);
  const int m0 = blockIdx.y * 256;
  const int nz0 = blockIdx.x * 256;

  __shared__ bf16 As[2 * 256 * 64];
  __shared__ bf16 Bs[2 * 256 * 64];

  const int tid = threadIdx.x;
  const int wave = tid >> 6, lane = tid & 63;
  const int l15 = lane & 15, quad = lane >> 4;
  const int wm = wave >> 2, wn = wave & 3;

  const int srow = tid >> 3;  // 0..63
  const int sch = tid & 7;
  const bf16* Ab = A + (size_t)(m0 + srow) * Csz + (sch ^ (srow & 7)) * 8;
  const bf16* Bb = Bt + (size_t)(nz0 + srow) * Csz + (sch ^ (srow & 7)) * 8;

#define STG(Xb, lds, lbuf, hh, tt)                                           \
  {                                                                          \
    GLOAD_LDS16((Xb) + (size_t)((hh)*128) * Csz + (size_t)(tt)*64,           \
                &(lds)[(lbuf) * (256 * 64) + (hh)*8192 + tid * 8]);          \
    GLOAD_LDS16((Xb) + (size_t)((hh)*128 + 64) * Csz + (size_t)(tt)*64,     \
                &(lds)[(lbuf) * (256 * 64) + (hh)*8192 + 4096 + tid * 8]);  \
  }
#define RD_A(dst, lbuf, i2, ks)                                              \
  dst = *(const bf16x8*)&As[(lbuf) * (256 * 64) +                            \
                            (wm * 128 + (i2)*16 + l15) * 64 +                \
                            ((((ks)*4 + quad) ^ (l15 & 7)) * 8)];
#define RD_B(dst, lbuf, j2, ks)                                              \
  dst = *(const bf16x8*)&Bs[(lbuf) * (256 * 64) +                            \
                            (wn * 64 + (j2)*16 + l15) * 64 +                 \
                            ((((ks)*4 + quad) ^ (l15 & 7)) * 8)];

  float4v acc[8][4];
#pragma unroll
  for (int i = 0; i < 8; ++i)
#pragma unroll
    for (int j = 0; j < 4; ++j) acc[i][j] = (float4v){0.f, 0.f, 0.f, 0.f};

  // prologue: tile0 all 4 halves, tile1 A-halves (12 loads/thread total)
  STG(Ab, As, 0, 0, 0);
  STG(Ab, As, 0, 1, 0);
  STG(Bb, Bs, 0, 0, 0);
  STG(Bb, Bs, 0, 1, 0);
  STG(Ab, As, 1, 0, 1);
  STG(Ab, As, 1, 1, 1);
  asm volatile("s_waitcnt vmcnt(4)" ::: "memory");
  __builtin_amdgcn_s_barrier();
  __builtin_amdgcn_sched_barrier(0);

#pragma unroll 1
  for (int t = 0; t < NT; ++t) {
    const int bsel = t & 1;
    bf16x8 af0[4][2], af1[4][2], bf0[2][2], bf1[2][2];

    // ---- P1: quadrant (0,0) --------------------------------------------
#pragma unroll
    for (int i = 0; i < 4; ++i) {
      RD_A(af0[i][0], bsel, i, 0);
      RD_A(af0[i][1], bsel, i, 1);
    }
#pragma unroll
    for (int j = 0; j < 2; ++j) {
      RD_B(bf0[j][0], bsel, j, 0);
      RD_B(bf0[j][1], bsel, j, 1);
    }
    if (t + 1 < NT) STG(Bb, Bs, bsel ^ 1, 0, t + 1);
    __builtin_amdgcn_s_barrier();
    asm volatile("s_waitcnt lgkmcnt(0)" ::: "memory");
    __builtin_amdgcn_sched_barrier(0);
    __builtin_amdgcn_s_setprio(1);
#pragma unroll
    for (int i = 0; i < 4; ++i)
#pragma unroll
      for (int j = 0; j < 2; ++j) {
        acc[i][j] = MFMA16(af0[i][0], bf0[j][0], acc[i][j]);
        acc[i][j] = MFMA16(af0[i][1], bf0[j][1], acc[i][j]);
      }
    __builtin_amdgcn_s_setprio(0);
    __builtin_amdgcn_s_barrier();

    // ---- P2: quadrant (1,0) --------------------------------------------
#pragma unroll
    for (int i = 0; i < 4; ++i) {
      RD_A(af1[i][0], bsel, 4 + i, 0);
      RD_A(af1[i][1], bsel, 4 + i, 1);
    }
    if (t + 1 < NT) STG(Bb, Bs, bsel ^ 1, 1, t + 1);
    __builtin_amdgcn_s_barrier();
    asm volatile("s_waitcnt lgkmcnt(0)" ::: "memory");
    __builtin_amdgcn_sched_barrier(0);
    __builtin_amdgcn_s_setprio(1);
#pragma unroll
    for (int i = 0; i < 4; ++i)
#pragma unroll
      for (int j = 0; j < 2; ++j) {
        acc[4 + i][j] = MFMA16(af1[i][0], bf0[j][0], acc[4 + i][j]);
        acc[4 + i][j] = MFMA16(af1[i][1], bf0[j][1], acc[4 + i][j]);
      }
    __builtin_amdgcn_s_setprio(0);
    __builtin_amdgcn_s_barrier();

    // ---- P3: quadrant (0,1) --------------------------------------------
#pragma unroll
    for (int j = 0; j < 2; ++j) {
      RD_B(bf1[j][0], bsel, 2 + j, 0);
      RD_B(bf1[j][1], bsel, 2 + j, 1);
    }
    if (t + 2 < NT) STG(Ab, As, bsel, 0, t + 2);
    __builtin_amdgcn_s_barrier();
    asm volatile("s_waitcnt lgkmcnt(0)" ::: "memory");
    __builtin_amdgcn_sched_barrier(0);
    __builtin_amdgcn_s_setprio(1);
#pragma unroll
    for (int i = 0; i < 4; ++i)
#pragma unroll
      for (int j = 0; j < 2; ++j) {
        acc[i][2 + j] = MFMA16(af0[i][0], bf1[j][0], acc[i][2 + j]);
        acc[i][2 + j] = MFMA16(af0[i][1], bf1[j][1], acc[i][2 + j]);
      }
    __builtin_amdgcn_s_setprio(0);
    __builtin_amdgcn_s_barrier();

    // ---- P4: quadrant (1,1) --------------------------------------------
    if (t + 2 < NT) STG(Ab, As, bsel, 1, t + 2);
    __builtin_amdgcn_s_barrier();
    __builtin_amdgcn_s_setprio(1);
#pragma unroll
    for (int i = 0; i < 4; ++i)
#pragma unroll
      for (int j = 0; j < 2; ++j) {
        acc[4 + i][2 + j] = MFMA16(af1[i][0], bf1[j][0], acc[4 + i][2 + j]);
        acc[4 + i][2 + j] = MFMA16(af1[i][1], bf1[j][1], acc[4 + i][2 + j]);
      }
    __builtin_amdgcn_s_setprio(0);
    if (t + 2 < NT) {
      asm volatile("s_waitcnt vmcnt(4)" ::: "memory");
    } else if (t + 1 < NT) {
      asm volatile("s_waitcnt vmcnt(0)" ::: "memory");
    }
    __builtin_amdgcn_s_barrier();
    __builtin_amdgcn_sched_barrier(0);
  }
#undef STG
#undef RD_A
#undef RD_B

  const int omb0 = m0 + wm * 128 + quad * 4;
  const int onb0 = nz0 + wn * 64 + l15;
  if (z == 2) {
#pragma unroll
    for (int j = 0; j < 4; ++j) {
      const int n = onb0 + j * 16;
      const float bj = bias[n];
#pragma unroll
      for (int i = 0; i < 8; ++i) {
        const int mrow = omb0 + i * 16;
        const int bb = mrow >> 11, tt = mrow & (Tsz - 1);
        union { bf16 h[4]; uint2 u; } pk;
#pragma unroll
        for (int r = 0; r < 4; ++r) pk.h[r] = (bf16)(acc[i][j][r] + bj);
        *(uint2*)(Vt + ((size_t)(bb * 1024 + n)) * Tsz + tt) = pk.u;
      }
    }
  } else {
    bf16* C = z == 0 ? C0 : C1;
    const float osc = z == 0 ? 0.180336880111124f : 1.0f;  // 0.125*log2(e)
#pragma unroll
    for (int j = 0; j < 4; ++j) {
      const float bj = bias[onb0 + j * 16];
#pragma unroll
      for (int i = 0; i < 8; ++i) {
#pragma unroll
        for (int r = 0; r < 4; ++r) {
          const float v = (acc[i][j][r] + bj) * osc;
          C[(size_t)(omb0 + i * 16 + r) * Csz + onb0 + j * 16] = (bf16)v;
        }
      }
    }
  }
}

// ---------------------------------------------------------------------------
// bf16 MFMA GEMM (m97 structure): kept for the output projection.
// ---------------------------------------------------------------------------
template <typename OutT, bool VTR>
__global__ __launch_bounds__(256) void gemm_mfma(
    const bf16* __restrict__ A0, const bf16* __restrict__ A1,
    const bf16* __restrict__ A2, const bf16* __restrict__ Wt,
    const float* __restrict__ b0, const float* __restrict__ b1,
    const float* __restrict__ b2, OutT* __restrict__ C0,
    OutT* __restrict__ C1, OutT* __restrict__ C2, int M, int N, int K) {
  const int z = blockIdx.z;
  const bf16* A = z == 0 ? A0 : (z == 1 ? A1 : A2);
  const float* bias = z == 0 ? b0 : (z == 1 ? b1 : b2);
  OutT* C = z == 0 ? C0 : (z == 1 ? C1 : C2);
  const bf16* Bt = Wt + (size_t)z * N * K;
  const float osc = (VTR && z == 0) ? 0.180336880111124f : 1.0f;

  __shared__ bf16 As[128 * 32];
  __shared__ bf16 Bs[128 * 32];
  const int tid = threadIdx.x;
  const int wave = tid >> 6, lane = tid & 63;
  const int l15 = lane & 15, quad = lane >> 4;
  const int m0 = blockIdx.y * 128, n0 = blockIdx.x * 128;
  const int wm = (wave >> 1) * 64, wn = (wave & 1) * 64;
  const int srow = tid >> 2, schunk = tid & 3;

  float4v acc[4][4];
#pragma unroll
  for (int i = 0; i < 4; ++i)
#pragma unroll
    for (int j = 0; j < 4; ++j) acc[i][j] = (float4v){0.f, 0.f, 0.f, 0.f};

  for (int k0 = 0; k0 < K; k0 += 32) {
    __syncthreads();
#pragma unroll
    for (int p = 0; p < 2; ++p) {
      const int row = p * 64 + srow;
      GLOAD_LDS16(A + (size_t)(m0 + row) * K + k0 + schunk * 8,
                  &As[(p * 256 + tid) * 8]);
      GLOAD_LDS16(Bt + (size_t)(n0 + row) * K + k0 + schunk * 8,
                  &Bs[(p * 256 + tid) * 8]);
    }
    __syncthreads();

    bf16x8 af[4], bfr[4];
#pragma unroll
    for (int i = 0; i < 4; ++i)
      af[i] = *(const bf16x8*)&As[(wm + i * 16 + l15) * 32 + quad * 8];
#pragma unroll
    for (int j = 0; j < 4; ++j)
      bfr[j] = *(const bf16x8*)&Bs[(wn + j * 16 + l15) * 32 + quad * 8];
#pragma unroll
    for (int i = 0; i < 4; ++i)
#pragma unroll
      for (int j = 0; j < 4; ++j)
        acc[i][j] = MFMA16(af[i], bfr[j], acc[i][j]);
  }

  const int omb = m0 + wm + quad * 4;
  const int onb = n0 + wn + l15;
  if (VTR && z == 2) {
#pragma unroll
    for (int j = 0; j < 4; ++j) {
      const int n = onb + j * 16;
      const float bj = bias[n];
#pragma unroll
      for (int i = 0; i < 4; ++i) {
        const int mrow = omb + i * 16;
        const int bb = mrow >> 11, t = mrow & (Tsz - 1);
        union { bf16 h[4]; uint2 u; } pk;
#pragma unroll
        for (int r = 0; r < 4; ++r) pk.h[r] = (bf16)(acc[i][j][r] + bj);
        *(uint2*)((bf16*)C + ((size_t)(bb * 1024 + n)) * Tsz + t) = pk.u;
      }
    }
  } else {
#pragma unroll
    for (int j = 0; j < 4; ++j) {
      const float bj = bias[onb + j * 16];
#pragma unroll
      for (int i = 0; i < 4; ++i) {
#pragma unroll
        for (int r = 0; r < 4; ++r) {
          const float v = (acc[i][j][r] + bj) * osc;
          const size_t off = (size_t)(omb + i * 16 + r) * N + onb + j * 16;
          if constexpr (sizeof(OutT) == 2)
            C[off] = (OutT)v;
          else
            C[off] = v;
        }
      }
    }
  }
}

// ---------------------------------------------------------------------------
// Flash attention, bf16 MFMA, S^T formulation. R2 compute body + mapping;
// K/V DOUBLE-buffered: LDS 51200 -> 3 blocks/CU (round 4).
//   iter t: [stage t+1 -> buf^1] [compute buf] [vmcnt(0)] [barrier]
// WAR: buf^1 was read in iter t-1; each wave's reads retire before its own
// MFMAs (compiler lgkmcnt), which precede the iter-(t-1) barrier; the stage
// is issued after every wave crossed it.  RAW: vmcnt(0) at end of iter t
// retires tile t+1's loads (issued a full iteration earlier) pre-barrier.
// ---------------------------------------------------------------------------
__global__ __launch_bounds__(256) void attn_mfma(const bf16* __restrict__ Q,
                                                 const bf16* __restrict__ K,
                                                 const bf16* __restrict__ Vt,
                                                 bf16* __restrict__ Y) {
  __shared__ bf16 Ks[2][64 * 64];
  __shared__ bf16 Vs[2][64 * 64];
  __shared__ bf16 Ps[4][32 * 72];  // per-wave P[q][key], row stride 72

  const int bh = blockIdx.y;
  const int b = bh >> 4, h = bh & 15;
  // sum-balanced complementary mapping (R2, measured best): neighbors
  // (2c,2c+1) -> ranks (c, 15-c); layers y and y+16 complemented.
  int xr = (blockIdx.x & 1) ? (int)(gridDim.x - 1 - (blockIdx.x >> 1))
                            : (int)(blockIdx.x >> 1);
  if (bh >= 16) xr = (int)(gridDim.x - 1) - xr;
  const int i0 = xr * 128;
  const int tid = threadIdx.x;
  const int wave = tid >> 6, lane = tid & 63;
  const int l15 = lane & 15, quad = lane >> 4;

  const int srow = tid >> 3;  // 0..31
  const int sch = tid & 7;

  const bf16* kb = K + (size_t)b * Tsz * Csz + h * HDsz;
  const bf16* vb = Vt + (size_t)bh * HDsz * Tsz;

  const int qb = i0 + wave * 32;  // wave's first q row

  bf16x8 qf[2][2];
#pragma unroll
  for (int sub = 0; sub < 2; ++sub) {
    const bf16* qp =
        Q + ((size_t)(b * Tsz + qb + sub * 16 + l15)) * Csz + h * HDsz + quad * 8;
    qf[sub][0] = *(const bf16x8*)qp;
    qf[sub][1] = *(const bf16x8*)(qp + 32);
  }

  bf16x8 ones;
#pragma unroll
  for (int j = 0; j < 8; ++j) ones[j] = (bf16)1.0f;

  float4v Of[2][4];
  float4v accl[2];
#pragma unroll
  for (int sub = 0; sub < 2; ++sub) {
    accl[sub] = (float4v){0.f, 0.f, 0.f, 0.f};
#pragma unroll
    for (int nc = 0; nc < 4; ++nc) Of[sub][nc] = (float4v){0.f, 0.f, 0.f, 0.f};
  }

  const int ntile = i0 / 64 + 2;  // keys 0 .. i0+127 (>= 2 always)

  // stage K/V tile tt into LDS buffer bb: 4 loads/thread (2 K + 2 V)
#define STAGE_KV(tt, bb)                                                     \
  {                                                                          \
    _Pragma("unroll") for (int p = 0; p < 2; ++p) {                          \
      const int r = p * 32 + srow;                                           \
      const int c = sch ^ (r & 7);                                           \
      GLOAD_LDS16(kb + (size_t)((tt)*64 + r) * Csz + c * 8,                  \
                  &Ks[bb][(p * 256 + tid) * 8]);                             \
      GLOAD_LDS16(vb + (size_t)r * Tsz + (tt)*64 + c * 8,                    \
                  &Vs[bb][(p * 256 + tid) * 8]);                             \
    }                                                                        \
  }

  // prologue: tile 0 resident before first compute
  STAGE_KV(0, 0);
  asm volatile("s_waitcnt vmcnt(0)" ::: "memory");
  __builtin_amdgcn_s_barrier();
  __builtin_amdgcn_sched_barrier(0);

#pragma unroll 1
  for (int t = 0; t < ntile; ++t) {
    const int j0 = t * 64;
    const int buf = t & 1;
    if (t + 1 < ntile) STAGE_KV(t + 1, buf ^ 1);

    if (j0 <= qb + 31) {  // wave-uniform: skip fully-masked tiles
      // ---- S^T = K Q^T : C-layout S^T[key=j0+nc*16+quad*4+r][q=qb+sub*16+l15]
      float4v S[2][4];
#pragma unroll
      for (int nc = 0; nc < 4; ++nc) {
        const int row = nc * 16 + l15;
        const bf16x8 k0 =
            *(const bf16x8*)&Ks[buf][row * 64 + ((quad ^ (row & 7)) * 8)];
        const bf16x8 k1 =
            *(const bf16x8*)&Ks[buf][row * 64 + (((quad + 4) ^ (row & 7)) * 8)];
#pragma unroll
        for (int sub = 0; sub < 2; ++sub) {
          float4v a = (float4v){0.f, 0.f, 0.f, 0.f};
          a = MFMA16(k0, qf[sub][0], a);
          a = MFMA16(k1, qf[sub][1], a);
          S[sub][nc] = a;
        }
      }

      // ---- causal mask: key > q  (wave-uniform branch, near-diagonal only)
      if (j0 + 63 > qb) {
#pragma unroll
        for (int sub = 0; sub < 2; ++sub) {
          const int q = qb + sub * 16 + l15;
#pragma unroll
          for (int nc = 0; nc < 4; ++nc) {
            const int keyb = j0 + nc * 16 + quad * 4;
#pragma unroll
            for (int r = 0; r < 4; ++r)
              if (keyb + r > q) S[sub][nc][r] = -1e30f;
          }
        }
      }

      // ---- un-shifted exp2 numerator; P[q][key] -> LDS (b64, r contiguous)
#pragma unroll
      for (int sub = 0; sub < 2; ++sub) {
#pragma unroll
        for (int nc = 0; nc < 4; ++nc) {
          bf16x4 pk;
#pragma unroll
          for (int r = 0; r < 4; ++r)
            pk[r] = (bf16)__builtin_amdgcn_exp2f(S[sub][nc][r]);
          *(bf16x4*)&Ps[wave][(sub * 16 + l15) * 72 + nc * 16 + quad * 4] = pk;
        }
      }

      // ---- P^T B-frags (b128), l, and O^T += V^T P^T (same-wave LDS RAW) --
      bf16x8 pf[2][2];
#pragma unroll
      for (int sub = 0; sub < 2; ++sub) {
#pragma unroll
        for (int kc = 0; kc < 2; ++kc)
          pf[sub][kc] = *(const bf16x8*)
              &Ps[wave][(sub * 16 + l15) * 72 + kc * 32 + quad * 8];
        accl[sub] = MFMA16(ones, pf[sub][0], accl[sub]);
        accl[sub] = MFMA16(ones, pf[sub][1], accl[sub]);
      }
#pragma unroll
      for (int nc = 0; nc < 4; ++nc) {
        const int row = nc * 16 + l15;
#pragma unroll
        for (int kc = 0; kc < 2; ++kc) {
          const bf16x8 vf = *(const bf16x8*)
              &Vs[buf][row * 64 + (((kc * 4 + quad) ^ (row & 7)) * 8)];
#pragma unroll
          for (int sub = 0; sub < 2; ++sub)
            Of[sub][nc] = MFMA16(vf, pf[sub][kc], Of[sub][nc]);
        }
      }
    }

    // ---- gate: tile t+1 resident before next iter (issued 1 iter ago) ----
    if (t + 1 < ntile) {
      asm volatile("s_waitcnt vmcnt(0)" ::: "memory");
    }
    __builtin_amdgcn_sched_barrier(0);
    __builtin_amdgcn_s_barrier();
    __builtin_amdgcn_sched_barrier(0);
  }
#undef STAGE_KV

  // ---- epilogue: Y[q][h*64+d] = O^T[d][q] / l[q]  (8B stores, r contiguous)
#pragma unroll
  for (int sub = 0; sub < 2; ++sub) {
    const float rl = __builtin_amdgcn_rcpf(accl[sub][0]);
    const size_t rowoff =
        ((size_t)(b * Tsz + qb + sub * 16 + l15)) * Csz + h * HDsz;
#pragma unroll
    for (int nc = 0; nc < 4; ++nc) {
      union { bf16 h4[4]; uint2 u; } pk;
#pragma unroll
      for (int r = 0; r < 4; ++r) pk.h4[r] = (bf16)(Of[sub][nc][r] * rl);
      *(uint2*)(Y + rowoff + nc * 16 + quad * 4) = pk.u;
    }
  }
}

extern "C" void kernel_launch(void* const* d_in, const int* in_sizes, int n_in,
                              void* d_out, int out_size, void* d_ws,
                              size_t ws_size, hipStream_t stream) {
  const float* query = (const float*)d_in[0];
  const float* key = (const float*)d_in[1];
  const float* value = (const float*)d_in[2];
  // d_in[3] = att_mask (tril causal) -- hard-coded in attn kernel
  const float* Wq = (const float*)d_in[4];
  const float* bq = (const float*)d_in[5];
  const float* Wk = (const float*)d_in[6];
  const float* bk = (const float*)d_in[7];
  const float* Wv = (const float*)d_in[8];
  const float* bv = (const float*)d_in[9];
  const float* Wp = (const float*)d_in[10];
  const float* bp = (const float*)d_in[11];
  float* out = (float*)d_out;

  char* ws = (char*)d_ws;
  bf16* WT = (bf16*)(ws);
  bf16* vc = (bf16*)(ws + (8u << 20));
  bf16* Qp = (bf16*)(ws + (16u << 20));
  bf16* Kp = (bf16*)(ws + (24u << 20));
  bf16* Vt = (bf16*)(ws + (32u << 20));
  bf16* Yb = vc;
  bf16* qc = (bf16*)d_out;
  bf16* kc = (bf16*)((char*)d_out + (8u << 20));

  const int M = Bsz * Tsz;  // 4096

  cast3_bf16<<<dim3((M * Csz) / (256 * 8), 1, 3), dim3(256), 0, stream>>>(
      query, key, value, qc, kc, vc);
  wtrans_bf16<<<dim3(16, 16, 4), dim3(256), 0, stream>>>(Wq, Wk, Wv, Wp, WT);
  // batched QKV projection, 256^2 8-phase; z==0 pre-scales Q; z==2 -> Vt
  gemm256_qkv<<<dim3(Csz / 256, M / 256, 3), dim3(512), 0, stream>>>(
      qc, kc, vc, WT, bq, bk, bv, Qp, Kp, Vt);
  // flash attention (writes bf16 into Yb = old vc slot)
  attn_mfma<<<dim3(Tsz / 128, Bsz * Hsz), dim3(256), 0, stream>>>(Qp, Kp, Vt,
                                                                  Yb);
  // output projection (f32 into d_out)
  gemm_mfma<float, false><<<dim3(Csz / 128, M / 128, 1), dim3(256), 0, stream>>>(
      Yb, Yb, Yb, WT + 3u * (Csz * Csz), bp, bp, bp, out, out, out, M, Csz,
      Csz);
}